// Round 2
// baseline (1883.623 us; speedup 1.0000x reference)
//
#include <hip/hip_runtime.h>

// LSTMTrafficPredictor: fused 2-layer LSTM + FC head, fp32.
// B=2048, T=512, IN=4, H1=64, H2=32, FC=16, OUT=1.
// R1 design: BLK=512 threads, NB=8 batches/block, grid=256 (1 block/CU).
// K-split weight distribution so per-thread weights = 58 floats (register-
// resident; R0's 164/thread exceeded what the allocator would keep: VGPR=108).
//   layer1: thread t -> gate row r=t&255, K-half q=t>>8   (wih1:2 + whh1:32)
//   layer2: thread t -> gate row r2=t&127, K-quarter q2=t>>7 (wih2:16 + whh2:8)
// Partial sums combined via LDS in the update phases.
// x staged in LDS in 128-step chunks (16 KB) to stay under 64 KB static LDS.

#define T_LEN 512
#define IN_F  4
#define H1    64
#define H2    32
#define FCN   16
#define NB    8
#define BLK   512
#define CHUNK 128   // timesteps of x staged per refill

__device__ __forceinline__ float sigm(float x) {
    return 1.0f / (1.0f + __expf(-x));
}
__device__ __forceinline__ float tanh_(float x) {
    // 1 - 2/(e^{2x}+1): saturates correctly for large |x|
    return 1.0f - 2.0f / (__expf(2.0f * x) + 1.0f);
}

__global__ __launch_bounds__(BLK, 2)
void lstm_fused(const float* __restrict__ x,
                const float* __restrict__ Wih1, const float* __restrict__ Whh1,
                const float* __restrict__ bih1, const float* __restrict__ bhh1,
                const float* __restrict__ Wih2, const float* __restrict__ Whh2,
                const float* __restrict__ bih2, const float* __restrict__ bhh2,
                const float* __restrict__ fc1_w, const float* __restrict__ fc1_b,
                const float* __restrict__ fc2_w, const float* __restrict__ fc2_b,
                float* __restrict__ out)
{
    __shared__ __align__(16) float x_s[NB * CHUNK * IN_F];   // 16 KB
    __shared__ __align__(16) float g1p[2 * NB * 4 * H1];     // 16 KB
    __shared__ __align__(16) float g2p[4 * NB * 4 * H2];     // 16 KB
    __shared__ __align__(16) float h1_s[NB][H1];             // 2 KB
    __shared__ __align__(16) float h2_s[NB][H2];             // 1 KB
    __shared__ __align__(16) float b1_s[4 * H1];             // 1 KB
    __shared__ __align__(16) float b2_s[4 * H2];             // 0.5 KB

    const int t  = threadIdx.x;
    const int b0 = blockIdx.x * NB;

    // ---- roles ----
    const int r   = t & 255;        // layer1 gate row
    const int q   = t >> 8;         // layer1 K-half (0..1)
    const int qo1 = q * 32;         // h1 column offset
    const int r2  = t & 127;        // layer2 gate row
    const int q2  = t >> 7;         // layer2 K-quarter (0..3)
    const int qo2 = q2 * 16;        // h1 column offset for layer2
    const int qo2h = q2 * 8;        // h2 column offset for layer2

    // ---- weights into registers (58 floats/thread) ----
    float2 wx;                      // wih1 cols q*2, q*2+1 of row r
    float4 w1[8];                   // whh1 cols q*32..q*32+31 of row r
    float4 w2a[4];                  // wih2 cols q2*16..+15 of row r2
    float4 w2h[2];                  // whh2 cols q2*8..+7 of row r2
    wx = *(const float2*)&Wih1[r * IN_F + q * 2];
    #pragma unroll
    for (int j = 0; j < 8; ++j) w1[j] = *(const float4*)&Whh1[r * H1 + qo1 + j * 4];
    #pragma unroll
    for (int j = 0; j < 4; ++j) w2a[j] = *(const float4*)&Wih2[r2 * H1 + qo2 + j * 4];
    #pragma unroll
    for (int j = 0; j < 2; ++j) w2h[j] = *(const float4*)&Whh2[r2 * H2 + qo2h + j * 4];

    // ---- biases + state init ----
    if (t < 4 * H1) b1_s[t] = bih1[t] + bhh1[t];
    if (t < 4 * H2) b2_s[t] = bih2[t] + bhh2[t];
    (&h1_s[0][0])[t] = 0.f;                       // NB*H1 == 512 == BLK
    if (t < NB * H2) (&h2_s[0][0])[t] = 0.f;
    float c1 = 0.f;                               // state for (b=t>>6, u=t&63)
    float c2 = 0.f;                               // state for (b=t>>5, u=t&31), t<256

    const float4* xg4 = (const float4*)x;         // one float4 per timestep
    float4* xs4 = (float4*)x_s;                   // [NB][CHUNK]
    const float2* xs2 = (const float2*)x_s;

    // ================= main recurrence =================
    for (int s = 0; s < T_LEN; ++s) {
        const int sc = s & (CHUNK - 1);
        if (sc == 0) {
            // refill x chunk: NB*CHUNK float4 = 1024 -> 2 per thread
            #pragma unroll
            for (int i = 0; i < (NB * CHUNK) / BLK; ++i) {
                const int idx = t + i * BLK;
                const int b = idx >> 7, j = idx & (CHUNK - 1);
                xs4[idx] = xg4[(size_t)(b0 + b) * T_LEN + s + j];
            }
            __syncthreads();
        }

        // ---- Phase A: layer1 partial gates (row r, K-half q, all NB batches) ----
        float a[NB];
        #pragma unroll
        for (int b = 0; b < NB; ++b) {
            const float2 xv = xs2[(b * CHUNK + sc) * 2 + q];
            a[b] = fmaf(wx.y, xv.y, wx.x * xv.x);
        }
        #pragma unroll
        for (int j4 = 0; j4 < 8; ++j4) {
            #pragma unroll
            for (int b = 0; b < NB; ++b) {
                const float4 hv = *(const float4*)&h1_s[b][qo1 + j4 * 4];
                a[b] = fmaf(w1[j4].x, hv.x, a[b]);
                a[b] = fmaf(w1[j4].y, hv.y, a[b]);
                a[b] = fmaf(w1[j4].z, hv.z, a[b]);
                a[b] = fmaf(w1[j4].w, hv.w, a[b]);
            }
        }
        #pragma unroll
        for (int b = 0; b < NB; ++b) g1p[q * (NB * 4 * H1) + b * (4 * H1) + r] = a[b];
        __syncthreads();

        // ---- Phase B: layer1 state update (b=t>>6, u=t&63) ----
        {
            const int b = t >> 6, u = t & (H1 - 1);
            const float* g0 = &g1p[b * (4 * H1)];
            const float* g1 = &g1p[NB * 4 * H1 + b * (4 * H1)];
            const float gi = sigm(g0[u]           + g1[u]           + b1_s[u]);
            const float gf = sigm(g0[H1 + u]      + g1[H1 + u]      + b1_s[H1 + u]);
            const float gg = tanh_(g0[2 * H1 + u] + g1[2 * H1 + u]  + b1_s[2 * H1 + u]);
            const float go = sigm(g0[3 * H1 + u]  + g1[3 * H1 + u]  + b1_s[3 * H1 + u]);
            c1 = fmaf(gf, c1, gi * gg);
            h1_s[b][u] = go * tanh_(c1);
        }
        __syncthreads();

        // ---- Phase C: layer2 partial gates (row r2, K-quarter q2, all NB batches) ----
        float a2[NB];
        #pragma unroll
        for (int b = 0; b < NB; ++b) a2[b] = 0.f;
        #pragma unroll
        for (int j4 = 0; j4 < 4; ++j4) {
            #pragma unroll
            for (int b = 0; b < NB; ++b) {
                const float4 hv = *(const float4*)&h1_s[b][qo2 + j4 * 4];
                a2[b] = fmaf(w2a[j4].x, hv.x, a2[b]);
                a2[b] = fmaf(w2a[j4].y, hv.y, a2[b]);
                a2[b] = fmaf(w2a[j4].z, hv.z, a2[b]);
                a2[b] = fmaf(w2a[j4].w, hv.w, a2[b]);
            }
        }
        #pragma unroll
        for (int j4 = 0; j4 < 2; ++j4) {
            #pragma unroll
            for (int b = 0; b < NB; ++b) {
                const float4 hv = *(const float4*)&h2_s[b][qo2h + j4 * 4];
                a2[b] = fmaf(w2h[j4].x, hv.x, a2[b]);
                a2[b] = fmaf(w2h[j4].y, hv.y, a2[b]);
                a2[b] = fmaf(w2h[j4].z, hv.z, a2[b]);
                a2[b] = fmaf(w2h[j4].w, hv.w, a2[b]);
            }
        }
        #pragma unroll
        for (int b = 0; b < NB; ++b) g2p[q2 * (NB * 4 * H2) + b * (4 * H2) + r2] = a2[b];
        __syncthreads();

        // ---- Phase D: layer2 state update (t<256: b=t>>5, u=t&31) ----
        if (t < NB * H2) {
            const int b = t >> 5, u = t & (H2 - 1);
            float gi = b2_s[u], gf = b2_s[H2 + u], gg = b2_s[2 * H2 + u], go = b2_s[3 * H2 + u];
            #pragma unroll
            for (int qq = 0; qq < 4; ++qq) {
                const float* gp = &g2p[qq * (NB * 4 * H2) + b * (4 * H2)];
                gi += gp[u];
                gf += gp[H2 + u];
                gg += gp[2 * H2 + u];
                go += gp[3 * H2 + u];
            }
            gi = sigm(gi); gf = sigm(gf); gg = tanh_(gg); go = sigm(go);
            c2 = fmaf(gf, c2, gi * gg);
            h2_s[b][u] = go * tanh_(c2);
        }
        __syncthreads();
    }

    // ================= FC head on final h2 =================
    float* fc_s = g2p;   // reuse as [NB][FCN]
    if (t < NB * FCN) {
        const int b = t / FCN, j = t % FCN;
        float sacc = fc1_b[j];
        #pragma unroll
        for (int k = 0; k < H2; ++k)
            sacc = fmaf(fc1_w[j * H2 + k], h2_s[b][k], sacc);
        fc_s[b * FCN + j] = fmaxf(sacc, 0.f);
    }
    __syncthreads();
    if (t < NB) {
        float sacc = fc2_b[0];
        #pragma unroll
        for (int j = 0; j < FCN; ++j)
            sacc = fmaf(fc2_w[j], fc_s[t * FCN + j], sacc);
        out[b0 + t] = sacc;
    }
}

extern "C" void kernel_launch(void* const* d_in, const int* in_sizes, int n_in,
                              void* d_out, int out_size, void* d_ws, size_t ws_size,
                              hipStream_t stream) {
    const float* x     = (const float*)d_in[0];
    const float* Wih1  = (const float*)d_in[1];
    const float* Whh1  = (const float*)d_in[2];
    const float* bih1  = (const float*)d_in[3];
    const float* bhh1  = (const float*)d_in[4];
    const float* Wih2  = (const float*)d_in[5];
    const float* Whh2  = (const float*)d_in[6];
    const float* bih2  = (const float*)d_in[7];
    const float* bhh2  = (const float*)d_in[8];
    const float* fc1_w = (const float*)d_in[9];
    const float* fc1_b = (const float*)d_in[10];
    const float* fc2_w = (const float*)d_in[11];
    const float* fc2_b = (const float*)d_in[12];
    float* out = (float*)d_out;

    const int n_batch = 2048;
    dim3 grid(n_batch / NB), block(BLK);
    lstm_fused<<<grid, block, 0, stream>>>(x, Wih1, Whh1, bih1, bhh1,
                                           Wih2, Whh2, bih2, bhh2,
                                           fc1_w, fc1_b, fc2_w, fc2_b, out);
}

// Round 3
// 1327.438 us; speedup vs baseline: 1.4190x; 1.4190x over previous
//
#include <hip/hip_runtime.h>

// LSTMTrafficPredictor: fused 2-layer LSTM + FC head, fp32.
// B=2048, T=512, IN=4, H1=64, H2=32, FC=16, OUT=1.
// R2 design: BLK=512, NB=4 batches/block, grid=512 -> 2 blocks/CU (barrier
// overlap; R1's 1 block/CU exposed every barrier drain). K-split weights:
//   layer1: thread = (row r=t&255, K-half q=t>>8)    -> 34 floats
//   layer2: thread = (row r2=t&127, K-quarter q2=t>>7) -> 24 floats
// Weights PINNED in VGPRs via empty inline asm: R0/R1 showed the allocator
// sinks loop-invariant per-lane loads back into the loop (VGPR_Count 52 < 58
// needed). An asm def cannot be rematerialized as a load.
// 3 barriers/step: layer2-update of step s-1 is folded into phase A of step s.
// All of x staged in LDS once (32 KB). launch_bounds(512,4): 128-VGPR cap.

#define T_LEN 512
#define IN_F  4
#define H1    64
#define H2    32
#define FCN   16
#define NB    4
#define BLK   512

#define PIN(v) asm volatile("" : "+v"(v))

__device__ __forceinline__ float sigm(float x) {
    return 1.0f / (1.0f + __expf(-x));
}
__device__ __forceinline__ float tanh_(float x) {
    // 1 - 2/(e^{2x}+1): saturates correctly for large |x|
    return 1.0f - 2.0f / (__expf(2.0f * x) + 1.0f);
}

__global__ __launch_bounds__(BLK, 4)
void lstm_fused(const float* __restrict__ x,
                const float* __restrict__ Wih1, const float* __restrict__ Whh1,
                const float* __restrict__ bih1, const float* __restrict__ bhh1,
                const float* __restrict__ Wih2, const float* __restrict__ Whh2,
                const float* __restrict__ bih2, const float* __restrict__ bhh2,
                const float* __restrict__ fc1_w, const float* __restrict__ fc1_b,
                const float* __restrict__ fc2_w, const float* __restrict__ fc2_b,
                float* __restrict__ out)
{
    __shared__ __align__(16) float x_s[NB * T_LEN * IN_F];   // 32 KB
    __shared__ __align__(16) float g1p[2 * NB * 4 * H1];     // 8 KB  [q][b][256]
    __shared__ __align__(16) float g2p[4 * NB * 4 * H2];     // 8 KB  [q2][b][128]
    __shared__ __align__(16) float h1_s[NB][H1];             // 1 KB
    __shared__ __align__(16) float h2_s[NB][H2];             // 0.5 KB

    const int t  = threadIdx.x;
    const int b0 = blockIdx.x * NB;

    // ---- roles ----
    const int r    = t & 255;        // layer1 gate row
    const int q    = t >> 8;         // layer1 K-half (0..1)
    const int qo1  = q * 32;         // h1 column offset
    const int r2   = t & 127;        // layer2 gate row
    const int q2   = t >> 7;         // layer2 K-quarter (0..3)
    const int qo2  = q2 * 16;        // h1 column offset (layer2)
    const int qo2h = q2 * 8;         // h2 column offset (layer2)

    // ---- weights into registers (58 floats/thread), then PIN ----
    float2 wx = *(const float2*)&Wih1[r * IN_F + q * 2];
    float4 w1[8], w2a[4], w2h[2];
    #pragma unroll
    for (int j = 0; j < 8; ++j) w1[j] = *(const float4*)&Whh1[r * H1 + qo1 + j * 4];
    #pragma unroll
    for (int j = 0; j < 4; ++j) w2a[j] = *(const float4*)&Wih2[r2 * H1 + qo2 + j * 4];
    #pragma unroll
    for (int j = 0; j < 2; ++j) w2h[j] = *(const float4*)&Whh2[r2 * H2 + qo2h + j * 4];
    float b1r = (q == 0)  ? (bih1[r] + bhh1[r])   : 0.f;   // bias folded into q==0 partial
    float b2r = (q2 == 0) ? (bih2[r2] + bhh2[r2]) : 0.f;

    PIN(wx.x); PIN(wx.y); PIN(b1r); PIN(b2r);
    #pragma unroll
    for (int j = 0; j < 8; ++j) { PIN(w1[j].x); PIN(w1[j].y); PIN(w1[j].z); PIN(w1[j].w); }
    #pragma unroll
    for (int j = 0; j < 4; ++j) { PIN(w2a[j].x); PIN(w2a[j].y); PIN(w2a[j].z); PIN(w2a[j].w); }
    #pragma unroll
    for (int j = 0; j < 2; ++j) { PIN(w2h[j].x); PIN(w2h[j].y); PIN(w2h[j].z); PIN(w2h[j].w); }

    // ---- stage ALL of x for our NB batches (coalesced float4) ----
    {
        const float4* src = (const float4*)(x + (size_t)b0 * T_LEN * IN_F);
        float4* dst = (float4*)x_s;
        #pragma unroll
        for (int i = 0; i < (NB * T_LEN * IN_F / 4) / BLK; ++i)
            dst[t + i * BLK] = src[t + i * BLK];
    }

    // ---- init state ----
    float c1 = 0.f;                               // (t<256): b=t>>6, u=t&63
    float c2 = 0.f;                               // (t<128): b=t>>5, u=t&31
    if (t < NB * H1) (&h1_s[0][0])[t] = 0.f;
    if (t < NB * H2) (&h2_s[0][0])[t] = 0.f;
    __syncthreads();

    // ================= main recurrence (3 barriers/step) =================
    #pragma unroll 1
    for (int s = 0; s < T_LEN; ++s) {
        // ---- Phase D(s-1): layer2 state update, folded here (t<128) ----
        if (s > 0 && t < NB * H2) {
            const int b = t >> 5, u = t & (H2 - 1);
            float gi = 0.f, gf = 0.f, gg = 0.f, go = 0.f;
            #pragma unroll
            for (int qq = 0; qq < 4; ++qq) {
                const float* gp = &g2p[qq * (NB * 4 * H2) + b * (4 * H2)];
                gi += gp[u];
                gf += gp[H2 + u];
                gg += gp[2 * H2 + u];
                go += gp[3 * H2 + u];
            }
            gi = sigm(gi); gf = sigm(gf); gg = tanh_(gg); go = sigm(go);
            c2 = fmaf(gf, c2, gi * gg);
            h2_s[b][u] = go * tanh_(c2);
        }

        // ---- Phase A: layer1 partial gates (row r, K-half q, NB batches) ----
        float a[NB];
        #pragma unroll
        for (int b = 0; b < NB; ++b) {
            const float2 xv = *(const float2*)&x_s[b * (T_LEN * IN_F) + s * IN_F + q * 2];
            a[b] = fmaf(wx.y, xv.y, fmaf(wx.x, xv.x, b1r));
        }
        #pragma unroll
        for (int j4 = 0; j4 < 8; ++j4) {
            #pragma unroll
            for (int b = 0; b < NB; ++b) {
                const float4 hv = *(const float4*)&h1_s[b][qo1 + j4 * 4];
                a[b] = fmaf(w1[j4].x, hv.x, a[b]);
                a[b] = fmaf(w1[j4].y, hv.y, a[b]);
                a[b] = fmaf(w1[j4].z, hv.z, a[b]);
                a[b] = fmaf(w1[j4].w, hv.w, a[b]);
            }
        }
        #pragma unroll
        for (int b = 0; b < NB; ++b) g1p[q * (NB * 4 * H1) + b * (4 * H1) + r] = a[b];
        __syncthreads();

        // ---- Phase B: layer1 state update (t<256: b=t>>6, u=t&63) ----
        if (t < NB * H1) {
            const int b = t >> 6, u = t & (H1 - 1);
            const float* g0 = &g1p[b * (4 * H1)];
            const float* g1 = &g1p[NB * 4 * H1 + b * (4 * H1)];
            const float gi = sigm(g0[u]          + g1[u]);
            const float gf = sigm(g0[H1 + u]     + g1[H1 + u]);
            const float gg = tanh_(g0[2 * H1 + u] + g1[2 * H1 + u]);
            const float go = sigm(g0[3 * H1 + u]  + g1[3 * H1 + u]);
            c1 = fmaf(gf, c1, gi * gg);
            h1_s[b][u] = go * tanh_(c1);
        }
        __syncthreads();

        // ---- Phase C: layer2 partial gates (row r2, K-quarter q2, NB batches) ----
        float a2[NB];
        #pragma unroll
        for (int b = 0; b < NB; ++b) a2[b] = b2r;
        #pragma unroll
        for (int j4 = 0; j4 < 4; ++j4) {
            #pragma unroll
            for (int b = 0; b < NB; ++b) {
                const float4 hv = *(const float4*)&h1_s[b][qo2 + j4 * 4];
                a2[b] = fmaf(w2a[j4].x, hv.x, a2[b]);
                a2[b] = fmaf(w2a[j4].y, hv.y, a2[b]);
                a2[b] = fmaf(w2a[j4].z, hv.z, a2[b]);
                a2[b] = fmaf(w2a[j4].w, hv.w, a2[b]);
            }
        }
        #pragma unroll
        for (int j4 = 0; j4 < 2; ++j4) {
            #pragma unroll
            for (int b = 0; b < NB; ++b) {
                const float4 hv = *(const float4*)&h2_s[b][qo2h + j4 * 4];
                a2[b] = fmaf(w2h[j4].x, hv.x, a2[b]);
                a2[b] = fmaf(w2h[j4].y, hv.y, a2[b]);
                a2[b] = fmaf(w2h[j4].z, hv.z, a2[b]);
                a2[b] = fmaf(w2h[j4].w, hv.w, a2[b]);
            }
        }
        #pragma unroll
        for (int b = 0; b < NB; ++b) g2p[q2 * (NB * 4 * H2) + b * (4 * H2) + r2] = a2[b];
        __syncthreads();
    }

    // ---- final layer2 update (step T-1) ----
    if (t < NB * H2) {
        const int b = t >> 5, u = t & (H2 - 1);
        float gi = 0.f, gf = 0.f, gg = 0.f, go = 0.f;
        #pragma unroll
        for (int qq = 0; qq < 4; ++qq) {
            const float* gp = &g2p[qq * (NB * 4 * H2) + b * (4 * H2)];
            gi += gp[u];
            gf += gp[H2 + u];
            gg += gp[2 * H2 + u];
            go += gp[3 * H2 + u];
        }
        gi = sigm(gi); gf = sigm(gf); gg = tanh_(gg); go = sigm(go);
        c2 = fmaf(gf, c2, gi * gg);
        h2_s[b][u] = go * tanh_(c2);
    }
    __syncthreads();

    // ================= FC head on final h2 =================
    float* fc_s = g2p;   // reuse as [NB][FCN]
    if (t < NB * FCN) {
        const int b = t / FCN, j = t % FCN;
        float sacc = fc1_b[j];
        #pragma unroll
        for (int k = 0; k < H2; ++k)
            sacc = fmaf(fc1_w[j * H2 + k], h2_s[b][k], sacc);
        fc_s[b * FCN + j] = fmaxf(sacc, 0.f);
    }
    __syncthreads();
    if (t < NB) {
        float sacc = fc2_b[0];
        #pragma unroll
        for (int j = 0; j < FCN; ++j)
            sacc = fmaf(fc2_w[j], fc_s[t * FCN + j], sacc);
        out[b0 + t] = sacc;
    }
}

extern "C" void kernel_launch(void* const* d_in, const int* in_sizes, int n_in,
                              void* d_out, int out_size, void* d_ws, size_t ws_size,
                              hipStream_t stream) {
    const float* x     = (const float*)d_in[0];
    const float* Wih1  = (const float*)d_in[1];
    const float* Whh1  = (const float*)d_in[2];
    const float* bih1  = (const float*)d_in[3];
    const float* bhh1  = (const float*)d_in[4];
    const float* Wih2  = (const float*)d_in[5];
    const float* Whh2  = (const float*)d_in[6];
    const float* bih2  = (const float*)d_in[7];
    const float* bhh2  = (const float*)d_in[8];
    const float* fc1_w = (const float*)d_in[9];
    const float* fc1_b = (const float*)d_in[10];
    const float* fc2_w = (const float*)d_in[11];
    const float* fc2_b = (const float*)d_in[12];
    float* out = (float*)d_out;

    const int n_batch = 2048;
    dim3 grid(n_batch / NB), block(BLK);
    lstm_fused<<<grid, block, 0, stream>>>(x, Wih1, Whh1, bih1, bhh1,
                                           Wih2, Whh2, bih2, bhh2,
                                           fc1_w, fc1_b, fc2_w, fc2_b, out);
}